// Round 11
// baseline (51466.388 us; speedup 1.0000x reference)
//
#include <hip/hip_runtime.h>

typedef unsigned short u16;
typedef unsigned int u32;
typedef unsigned long long u64;
typedef float f32x2 __attribute__((ext_vector_type(2)));

#define BATCH 256
#define TT 512
#define HID 256
#define GATES 1024   // 4*HID
#define NEMB 512
#define VOC 27
#define KSF 68       // floats per 64-K slice incl 4-float pad
#define HROW 272     // 4*KSF floats per batch row; 1088B, 16B-aligned

__device__ __forceinline__ float bf1(u16 x){ union{u32 u; float f;} v; v.u = ((u32)x) << 16; return v.f; }
__device__ __forceinline__ u16 f2bf(float f){
  union{float f; u32 u;} v; v.f = f;
  u32 u = v.u;
  return (u16)((u + 0x7fffu + ((u >> 16) & 1u)) >> 16);
}
__device__ __forceinline__ float sigm(float x){ return 1.f / (1.f + __expf(-x)); }
__device__ __forceinline__ f32x2 lo2(float4 v){ f32x2 r; r.x = v.x; r.y = v.y; return r; }
__device__ __forceinline__ f32x2 hi2(float4 v){ f32x2 r; r.x = v.z; r.y = v.w; return r; }

// Sniff storage dtype of b_ih0 (1024 elems, |v| <= 1/16).
__global__ void k_detect(const u16* __restrict__ b, int* __restrict__ flag) {
  int bad = 0;
  for (int k = threadIdx.x; k < 512; k += 64)
    if (((b[2 * k] >> 7) & 0xFF) >= 127) bad = 1;
  unsigned long long m = __ballot(bad);   // single wave
  if (threadIdx.x == 0) flag[0] = (m != 0ULL) ? 0 : 1;
}

__global__ void k_convert(const void* __restrict__ src, float* __restrict__ dst,
                          int n, const int* __restrict__ flag) {
  int i = blockIdx.x * 256 + threadIdx.x;
  if (i >= n) return;
  dst[i] = flag[0] ? bf1(((const u16*)src)[i]) : ((const float*)src)[i];
}

// W0emb[v][g] = sum_i emb[v][i]*w_ih0[g][i] + b_ih0[g] + b_hh0[g]; emb row 26 := 0
__global__ void k_prep(const void* __restrict__ emb, const void* __restrict__ wih,
                       const void* __restrict__ bih, const void* __restrict__ bhh,
                       const int* __restrict__ flag, float* __restrict__ W0) {
  int idx = blockIdx.x * 256 + threadIdx.x;
  if (idx >= VOC * GATES) return;
  int v = idx >> 10, g = idx & (GATES - 1);
  int isbf = flag[0];
  float acc = isbf ? (bf1(((const u16*)bih)[g]) + bf1(((const u16*)bhh)[g]))
                   : (((const float*)bih)[g] + ((const float*)bhh)[g]);
  if (v != 26) {
    float s = 0.f;
    if (isbf) {
      const u16* e = (const u16*)emb + v * NEMB;
      const u16* w = (const u16*)wih + g * NEMB;
      for (int i = 0; i < NEMB; i++) s = fmaf(bf1(e[i]), bf1(w[i]), s);
    } else {
      const float* e = (const float*)emb + v * NEMB;
      const float* w = (const float*)wih + g * NEMB;
      for (int i = 0; i < NEMB; i++) s = fmaf(e[i], w[i], s);
    }
    acc += s;
  }
  W0[idx] = acc;
}

// Persistent fused 2-layer LSTM, 256 blocks x 1024 threads, 1 block/CU.
// *** R11: composite-model fix — all three measured walls at once:
//  (1) weight stream 192 KB/block/iter (radius-16 j-split; 3.4us VMEM @1GHz)
//  (2) single-writer flag sync, no contended RMW (R9's, ~3us)
//  (3) 4-gate register tiling: thread (j=tid>>6, tb=(tid>>2)&15, ks=tid&3)
//      owns the 4 gate rows of one j over K-slice 64 -> each staged h float4
//      feeds 4 rows; 768 ds_read_b128/CU/iter (~9us DS, overlaps VMEM).
//      Bank classes (4tb+ks+k) mod 8: 8 lanes/class with DISTINCT rows =
//      baseline b128 depth (no R10 conflict). ks in lane bits 0-1 ->
//      __shfl_xor(1/2) reduce; ks==0 lane inlines pointwise (no gs stage).
// Decomposition: 16 groups x 16 blocks; grp = bid>>4 owns batches
// [16grp,16grp+16); jq = bid&15 owns j [16jq,16jq+16).
// Skew (R9, proven): iter t = L0 step t + L1 step t-2; flags0 published
// before L1 gemm; flags1 waited with need t-2. Coherence: relaxed AGENT
// atomics only; __syncthreads drains vmcnt(0) before each publish.
__global__ __launch_bounds__(1024) void k_lstm(
    const int* __restrict__ ids, const float* __restrict__ W0,
    const float* __restrict__ whh0, const float* __restrict__ wih1,
    const float* __restrict__ whh1,
    const float* __restrict__ bih1, const float* __restrict__ bhh1,
    float* __restrict__ h0a, float* __restrict__ h0b,
    float* __restrict__ h1a, float* __restrict__ h1b,
    u32* __restrict__ bar)
{
  const int tid = threadIdx.x;
  const int bid = blockIdx.x;
  const int grp = bid >> 4;           // [0,16) batch group (16 batches)
  const int jq  = bid & 15;           // [0,16) j-chunk (16 j)
  const int wv  = tid >> 6;
  const int ln  = tid & 63;

  const int ks = tid & 3;             // K-slice [64ks, 64ks+64)
  const int tb = (tid >> 2) & 15;     // batch within group
  const int j  = tid >> 6;            // [0,16) j within chunk (== wave id)
  const int jj = jq * 16 + j;         // j in [0,256)

  __shared__ __align__(16) float hp0[2][16][HROW]; // h0[t-1]/h0[t-2] tiles
  __shared__ __align__(16) float hp1[16][HROW];    // h1[t-3] tile
  __shared__ int ids_s[16];

  const size_t ko = (size_t)ks * 64;
  const float4* wl0_0 = (const float4*)(whh0 + (size_t)(0 * 256 + jj) * HID + ko);
  const float4* wl0_1 = (const float4*)(whh0 + (size_t)(1 * 256 + jj) * HID + ko);
  const float4* wl0_2 = (const float4*)(whh0 + (size_t)(2 * 256 + jj) * HID + ko);
  const float4* wl0_3 = (const float4*)(whh0 + (size_t)(3 * 256 + jj) * HID + ko);
  const float4* wi_0 = (const float4*)(wih1 + (size_t)(0 * 256 + jj) * HID + ko);
  const float4* wi_1 = (const float4*)(wih1 + (size_t)(1 * 256 + jj) * HID + ko);
  const float4* wi_2 = (const float4*)(wih1 + (size_t)(2 * 256 + jj) * HID + ko);
  const float4* wi_3 = (const float4*)(wih1 + (size_t)(3 * 256 + jj) * HID + ko);
  const float4* wh_0 = (const float4*)(whh1 + (size_t)(0 * 256 + jj) * HID + ko);
  const float4* wh_1 = (const float4*)(whh1 + (size_t)(1 * 256 + jj) * HID + ko);
  const float4* wh_2 = (const float4*)(whh1 + (size_t)(2 * 256 + jj) * HID + ko);
  const float4* wh_3 = (const float4*)(whh1 + (size_t)(3 * 256 + jj) * HID + ko);

  float bs0 = bih1[0 * 256 + jj] + bhh1[0 * 256 + jj];
  float bs1 = bih1[1 * 256 + jj] + bhh1[1 * 256 + jj];
  float bs2 = bih1[2 * 256 + jj] + bhh1[2 * 256 + jj];
  float bs3 = bih1[3 * 256 + jj] + bhh1[3 * 256 + jj];

  // owner (ks==0) holds cell (grp*16+tb, jj); c-state in registers
  const int prow = (grp * 16 + tb) * HID + jj;
  const bool owner = (ks == 0);
  float c0r = 0.f, c1r = 0.f;

  u32* flags0 = bar;                  // slot bid*16 u32 (64B apart), single-writer
  u32* flags1 = bar + 4096;

  for (int t = 0; t <= TT + 1; ++t) {
    // ---- wave0: poll the group's 16 flags (parallel lanes, no RMW) ----
    if (wv == 0) {
      u32 need = 0;
      const u32* fp = nullptr;
      if (ln < 16) {
        if (t >= 1 && t <= TT) { fp = flags0 + ((grp << 4) | ln) * 16; need = (u32)t; }
      } else if (ln < 32) {
        if (t >= 3) { fp = flags1 + ((grp << 4) | (ln - 16)) * 16; need = (u32)(t - 2); }
      }
      for (;;) {
        bool ok = true;
        if (need) ok = __hip_atomic_load(fp, __ATOMIC_RELAXED, __HIP_MEMORY_SCOPE_AGENT) >= need;
        if (__all(ok)) break;
        __builtin_amdgcn_s_sleep(2);
      }
    }
    __syncthreads();   // A: flags ok + prev-iter gemm done reading hp tiles

    // ---- stage tiles (relaxed agent loads; coalesced; padded rows) ----
    if (t <= TT) {
      const float* h0p = ((t + 1) & 1) ? h0b : h0a;      // h0[t-1]
      const u64* s0 = (const u64*)(h0p + grp * 16 * HID);
      float (*dst)[HROW] = hp0[t & 1];
      #pragma unroll
      for (int u = 0; u < 2; ++u) {
        int e = tid + 1024 * u;        // [0,2048) u64
        int sb = e >> 7, f = (e & 127) * 2;
        int mf = f + ((f >> 6) << 2);  // 64-float chunks -> 68-float slices
        u64 v = __hip_atomic_load(s0 + e, __ATOMIC_RELAXED, __HIP_MEMORY_SCOPE_AGENT);
        *(u64*)&dst[sb][mf] = v;
      }
      if (tid < 16) ids_s[tid] = (t < TT) ? ids[(grp * 16 + tid) * TT + t] : 0;
    }
    if (t >= 2) {
      const float* h1p = ((t + 1) & 1) ? h1b : h1a;      // h1[t-3]
      const u64* s1 = (const u64*)(h1p + grp * 16 * HID);
      #pragma unroll
      for (int u = 0; u < 2; ++u) {
        int e = tid + 1024 * u;
        int sb = e >> 7, f = (e & 127) * 2;
        int mf = f + ((f >> 6) << 2);
        u64 v = __hip_atomic_load(s1 + e, __ATOMIC_RELAXED, __HIP_MEMORY_SCOPE_AGENT);
        *(u64*)&hp1[sb][mf] = v;
      }
    }
    __syncthreads();   // B: tiles staged

    // ---- layer0, step t: 4 gate rows of one j x K-slice 64; inline pointwise ----
    if (t < TT) {
      const float4* h4 = (const float4*)&hp0[t & 1][tb][ks * KSF];
      f32x2 aL0={0,0}, aH0={0,0}, aL1={0,0}, aH1={0,0};
      f32x2 aL2={0,0}, aH2={0,0}, aL3={0,0}, aH3={0,0};
      #pragma unroll 4
      for (int k = 0; k < 16; ++k) {
        float4 hv = h4[k];
        float4 q0 = wl0_0[k], q1 = wl0_1[k], q2 = wl0_2[k], q3 = wl0_3[k];
        aL0 = lo2(q0) * lo2(hv) + aL0; aH0 = hi2(q0) * hi2(hv) + aH0;
        aL1 = lo2(q1) * lo2(hv) + aL1; aH1 = hi2(q1) * hi2(hv) + aH1;
        aL2 = lo2(q2) * lo2(hv) + aL2; aH2 = hi2(q2) * hi2(hv) + aH2;
        aL3 = lo2(q3) * lo2(hv) + aL3; aH3 = hi2(q3) * hi2(hv) + aH3;
      }
      float s0 = aL0.x + aL0.y + aH0.x + aH0.y;
      float s1 = aL1.x + aL1.y + aH1.x + aH1.y;
      float s2 = aL2.x + aL2.y + aH2.x + aH2.y;
      float s3 = aL3.x + aL3.y + aH3.x + aH3.y;
      s0 += __shfl_xor(s0, 1); s0 += __shfl_xor(s0, 2);
      s1 += __shfl_xor(s1, 1); s1 += __shfl_xor(s1, 2);
      s2 += __shfl_xor(s2, 1); s2 += __shfl_xor(s2, 2);
      s3 += __shfl_xor(s3, 1); s3 += __shfl_xor(s3, 2);
      if (owner) {
        const float* xr = W0 + (size_t)ids_s[tb] * GATES + jj;
        float gi = sigm(s0 + xr[0]);
        float gf = sigm(s1 + xr[256]);
        float gg = tanhf(s2 + xr[512]);
        float go = sigm(s3 + xr[768]);
        c0r = fmaf(gf, c0r, gi * gg);
        float* h0n = (t & 1) ? h0b : h0a;
        __hip_atomic_store(&h0n[prow], go * tanhf(c0r),
                           __ATOMIC_RELAXED, __HIP_MEMORY_SCOPE_AGENT);
      }
    }
    __syncthreads();   // C: drains vmcnt(0) -> h0 stores at coherence point
    if (tid == 0 && t < TT)
      __hip_atomic_store(flags0 + bid * 16, (u32)(t + 1),
                         __ATOMIC_RELAXED, __HIP_MEMORY_SCOPE_AGENT);

    // ---- layer1, step t-2: x = hp0 prev buffer, h = hp1; inline pointwise ----
    if (t >= 2) {
      const float4* x4 = (const float4*)&hp0[(t - 1) & 1][tb][ks * KSF];
      const float4* h4 = (const float4*)&hp1[tb][ks * KSF];
      f32x2 aL0={0,0}, aH0={0,0}, aL1={0,0}, aH1={0,0};
      f32x2 aL2={0,0}, aH2={0,0}, aL3={0,0}, aH3={0,0};
      #pragma unroll 4
      for (int k = 0; k < 16; ++k) {
        float4 xv = x4[k], hv = h4[k];
        float4 qi0 = wi_0[k], qi1 = wi_1[k], qi2 = wi_2[k], qi3 = wi_3[k];
        aL0 = lo2(qi0) * lo2(xv) + aL0; aH0 = hi2(qi0) * hi2(xv) + aH0;
        aL1 = lo2(qi1) * lo2(xv) + aL1; aH1 = hi2(qi1) * hi2(xv) + aH1;
        aL2 = lo2(qi2) * lo2(xv) + aL2; aH2 = hi2(qi2) * hi2(xv) + aH2;
        aL3 = lo2(qi3) * lo2(xv) + aL3; aH3 = hi2(qi3) * hi2(xv) + aH3;
        float4 qh0 = wh_0[k], qh1 = wh_1[k], qh2 = wh_2[k], qh3 = wh_3[k];
        aL0 = lo2(qh0) * lo2(hv) + aL0; aH0 = hi2(qh0) * hi2(hv) + aH0;
        aL1 = lo2(qh1) * lo2(hv) + aL1; aH1 = hi2(qh1) * hi2(hv) + aH1;
        aL2 = lo2(qh2) * lo2(hv) + aL2; aH2 = hi2(qh2) * hi2(hv) + aH2;
        aL3 = lo2(qh3) * lo2(hv) + aL3; aH3 = hi2(qh3) * hi2(hv) + aH3;
      }
      float s0 = aL0.x + aL0.y + aH0.x + aH0.y;
      float s1 = aL1.x + aL1.y + aH1.x + aH1.y;
      float s2 = aL2.x + aL2.y + aH2.x + aH2.y;
      float s3 = aL3.x + aL3.y + aH3.x + aH3.y;
      s0 += __shfl_xor(s0, 1); s0 += __shfl_xor(s0, 2);
      s1 += __shfl_xor(s1, 1); s1 += __shfl_xor(s1, 2);
      s2 += __shfl_xor(s2, 1); s2 += __shfl_xor(s2, 2);
      s3 += __shfl_xor(s3, 1); s3 += __shfl_xor(s3, 2);
      if (owner) {
        float gi = sigm(s0 + bs0);
        float gf = sigm(s1 + bs1);
        float gg = tanhf(s2 + bs2);
        float go = sigm(s3 + bs3);
        c1r = fmaf(gf, c1r, gi * gg);
        float* h1n = (t & 1) ? h1b : h1a;   // parity of s = t-2
        __hip_atomic_store(&h1n[prow], go * tanhf(c1r),
                           __ATOMIC_RELAXED, __HIP_MEMORY_SCOPE_AGENT);
      }
    }
    __syncthreads();   // D: drains vmcnt(0) -> h1 stores at coherence point
    if (tid == 0 && t >= 2 && t <= TT)
      __hip_atomic_store(flags1 + bid * 16, (u32)(t - 1),
                         __ATOMIC_RELAXED, __HIP_MEMORY_SCOPE_AGENT);
  }
}

// MLP head: out[b] = fc2_w . relu(fc1_w @ h[b] + fc1_b) + fc2_b
__global__ __launch_bounds__(128) void k_fc(
    const float* __restrict__ hfin,
    const void* __restrict__ fc1w, const void* __restrict__ fc1b,
    const void* __restrict__ fc2w, const void* __restrict__ fc2b,
    const int* __restrict__ flag, void* __restrict__ out) {
  int b = blockIdx.x, j = threadIdx.x;  // 128 threads
  __shared__ float red[128];
  const float* h = hfin + b * HID;
  int isbf = flag[0];
  float acc = isbf ? bf1(((const u16*)fc1b)[j]) : ((const float*)fc1b)[j];
  if (isbf) {
    const u16* w = (const u16*)fc1w + j * HID;
    for (int k = 0; k < HID; k++) acc = fmaf(bf1(w[k]), h[k], acc);
  } else {
    const float* w = (const float*)fc1w + j * HID;
    for (int k = 0; k < HID; k++) acc = fmaf(w[k], h[k], acc);
  }
  acc = fmaxf(acc, 0.f);
  float w2 = isbf ? bf1(((const u16*)fc2w)[j]) : ((const float*)fc2w)[j];
  red[j] = acc * w2;
  __syncthreads();
  for (int s = 64; s > 0; s >>= 1) {
    if (j < s) red[j] += red[j + s];
    __syncthreads();
  }
  if (j == 0) {
    float b2 = isbf ? bf1(((const u16*)fc2b)[0]) : ((const float*)fc2b)[0];
    float r = red[0] + b2;
    if (isbf) ((u16*)out)[b] = f2bf(r);
    else      ((float*)out)[b] = r;
  }
}

extern "C" void kernel_launch(void* const* d_in, const int* in_sizes, int n_in,
                              void* d_out, int out_size, void* d_ws, size_t ws_size,
                              hipStream_t stream) {
  const int* ids   = (const int*)d_in[0];
  const void* emb  = d_in[1];
  const void* wih0 = d_in[2];
  const void* whh0 = d_in[3];
  const void* bih0 = d_in[4];
  const void* bhh0 = d_in[5];
  const void* wih1 = d_in[6];
  const void* whh1 = d_in[7];
  const void* bih1 = d_in[8];
  const void* bhh1 = d_in[9];
  const void* fc1w = d_in[10];
  const void* fc1b = d_in[11];
  const void* fc2w = d_in[12];
  const void* fc2b = d_in[13];

  float* ws = (float*)d_ws;
  int*   flag    = (int*)ws;                  // 16-float pad
  float* W0emb   = ws + 16;                   // 27648
  float* whh0_f  = W0emb  + VOC * GATES;      // 262144
  float* wih1_f  = whh0_f + GATES * HID;      // 262144
  float* whh1_f  = wih1_f + GATES * HID;      // 262144
  float* bih1_f  = whh1_f + GATES * HID;      // 1024
  float* bhh1_f  = bih1_f + GATES;            // 1024
  float* h0A = bhh1_f + GATES;                // 65536 each below
  float* h0B = h0A + BATCH * HID;
  float* c0  = h0B + BATCH * HID;             // reused as flag arrays
  float* h1A = c0  + BATCH * HID;
  float* h1B = h1A + BATCH * HID;
  float* c1  = h1B + BATCH * HID;
  u32*   bar = (u32*)c0;                      // flags0[256*16], flags1[256*16]

  k_detect<<<1, 64, 0, stream>>>((const u16*)bih0, flag);

  k_convert<<<(GATES * HID + 255) / 256, 256, 0, stream>>>(whh0, whh0_f, GATES * HID, flag);
  k_convert<<<(GATES * HID + 255) / 256, 256, 0, stream>>>(wih1, wih1_f, GATES * HID, flag);
  k_convert<<<(GATES * HID + 255) / 256, 256, 0, stream>>>(whh1, whh1_f, GATES * HID, flag);
  k_convert<<<(GATES + 255) / 256, 256, 0, stream>>>(bih1, bih1_f, GATES, flag);
  k_convert<<<(GATES + 255) / 256, 256, 0, stream>>>(bhh1, bhh1_f, GATES, flag);

  // zero h0A,h0B,c0(=flags),h1A,h1B,c1 — also resets flags each replay
  hipMemsetAsync(h0A, 0, (size_t)6 * BATCH * HID * sizeof(float), stream);

  k_prep<<<(VOC * GATES + 255) / 256, 256, 0, stream>>>(emb, wih0, bih0, bhh0, flag, W0emb);

  k_lstm<<<256, 1024, 0, stream>>>(ids, W0emb, whh0_f, wih1_f, whh1_f,
                                   bih1_f, bhh1_f, h0A, h0B, h1A, h1B, bar);

  // L1 step 511 computed at iter t=513 (odd) -> stored into h1B
  k_fc<<<BATCH, 128, 0, stream>>>(h1B, fc1w, fc1b, fc2w, fc2b, flag, d_out);
}

// Round 12
// 13173.845 us; speedup vs baseline: 3.9067x; 3.9067x over previous
//
#include <hip/hip_runtime.h>

typedef unsigned short u16;
typedef unsigned int u32;
typedef unsigned long long u64;
typedef float f32x2 __attribute__((ext_vector_type(2)));

#define BATCH 256
#define TT 512
#define HID 256
#define GATES 1024   // 4*HID
#define NEMB 512
#define VOC 27
#define HPAD 260     // 1040B row: 16B aligned, 2-way LDS conflict max (free)

__device__ __forceinline__ float bf1(u16 x){ union{u32 u; float f;} v; v.u = ((u32)x) << 16; return v.f; }
__device__ __forceinline__ u16 f2bf(float f){
  union{float f; u32 u;} v; v.f = f;
  u32 u = v.u;
  return (u16)((u + 0x7fffu + ((u >> 16) & 1u)) >> 16);
}
__device__ __forceinline__ float sigm(float x){ return 1.f / (1.f + __expf(-x)); }
__device__ __forceinline__ f32x2 lo2(float4 v){ f32x2 r; r.x = v.x; r.y = v.y; return r; }
__device__ __forceinline__ f32x2 hi2(float4 v){ f32x2 r; r.x = v.z; r.y = v.w; return r; }

// Sniff storage dtype of b_ih0 (1024 elems, |v| <= 1/16).
__global__ void k_detect(const u16* __restrict__ b, int* __restrict__ flag) {
  int bad = 0;
  for (int k = threadIdx.x; k < 512; k += 64)
    if (((b[2 * k] >> 7) & 0xFF) >= 127) bad = 1;
  unsigned long long m = __ballot(bad);   // single wave
  if (threadIdx.x == 0) flag[0] = (m != 0ULL) ? 0 : 1;
}

__global__ void k_convert(const void* __restrict__ src, float* __restrict__ dst,
                          int n, const int* __restrict__ flag) {
  int i = blockIdx.x * 256 + threadIdx.x;
  if (i >= n) return;
  dst[i] = flag[0] ? bf1(((const u16*)src)[i]) : ((const float*)src)[i];
}

// W0emb[v][g] = sum_i emb[v][i]*w_ih0[g][i] + b_ih0[g] + b_hh0[g]; emb row 26 := 0
__global__ void k_prep(const void* __restrict__ emb, const void* __restrict__ wih,
                       const void* __restrict__ bih, const void* __restrict__ bhh,
                       const int* __restrict__ flag, float* __restrict__ W0) {
  int idx = blockIdx.x * 256 + threadIdx.x;
  if (idx >= VOC * GATES) return;
  int v = idx >> 10, g = idx & (GATES - 1);
  int isbf = flag[0];
  float acc = isbf ? (bf1(((const u16*)bih)[g]) + bf1(((const u16*)bhh)[g]))
                   : (((const float*)bih)[g] + ((const float*)bhh)[g]);
  if (v != 26) {
    float s = 0.f;
    if (isbf) {
      const u16* e = (const u16*)emb + v * NEMB;
      const u16* w = (const u16*)wih + g * NEMB;
      for (int i = 0; i < NEMB; i++) s = fmaf(bf1(e[i]), bf1(w[i]), s);
    } else {
      const float* e = (const float*)emb + v * NEMB;
      const float* w = (const float*)wih + g * NEMB;
      for (int i = 0; i < NEMB; i++) s = fmaf(e[i], w[i], s);
    }
    acc += s;
  }
  W0[idx] = acc;
}

// Persistent fused 2-layer LSTM, 256 blocks x 1024 threads, 1 block/CU.
// *** R12: R9 (best, 12.44 ms) with ONE change — the gemm decomposition.
// R9's one-gate-row-per-thread gemm read 1 LDS float per MAC: 3 MB/CU/iter
// through the 128 B/cy DS port ≈ 24 us — matching R9's 25.7 us period (the
// term shared by every flat round R2-R4/R8/R9). Now: 2-ROW PAIRING with
// CONCURRENT layer halves. Threads 0-511: layer0, thread (tb=tid&3,
// pr=tid>>2 in [0,128)) computes rows {pr, pr+128} sharing each h-read.
// Threads 512-1023: layer1 step t-2 concurrently (2 rows, K=512) — inputs
// (hp0 prev buffer, hp1) are already staged, so no extra barriers. LDS
// traffic halves to 1.5 MB/CU/iter (~12 us); issue stays full-lane.
// Lane layout keeps R9's proven broadcast LDS pattern (tb in lane bits 0-1).
// EVERYTHING else is R9 verbatim: 64 groups x 4 blocks, single-writer 64B
// flag slots, relaxed AGENT atomics only, __syncthreads drains vmcnt(0)
// before each publish, skew (L0 step t, L1 step t-2), buffer parities.
__global__ __launch_bounds__(1024) void k_lstm(
    const int* __restrict__ ids, const float* __restrict__ W0,
    const float* __restrict__ whh0, const float* __restrict__ wih1,
    const float* __restrict__ whh1,
    const float* __restrict__ bih1, const float* __restrict__ bhh1,
    float* __restrict__ h0a, float* __restrict__ h0b,
    float* __restrict__ h1a, float* __restrict__ h1b,
    u32* __restrict__ bar)
{
  const int tid = threadIdx.x;
  const int bid = blockIdx.x;
  const int grp = ((bid >> 3) << 1) | (bid & 1);  // [0,64) batch group (4 batches)
  const int jq  = (bid & 7) >> 1;                 // [0,4) j-quarter (64 j)
  const int wv  = tid >> 6;
  const int ln  = tid & 63;

  const int tb = tid & 3;             // batch within group (both halves)
  const int pr = (tid >> 2) & 127;    // row-pair slot [0,128)

  __shared__ __align__(16) float hp0[2][4][HPAD]; // h0[t-1]/h0[t-2] tiles
  __shared__ __align__(16) float hp1[4][HPAD];    // h1[t-3] tile
  __shared__ float gs0[256][5];       // layer0 gates [gate*64+j][tb]
  __shared__ float gs1[256][5];       // layer1 gates
  __shared__ int   ids_l[4][TT];      // all ids for this group's 4 batches

  // row indices for this thread's pair: r0 = pr, r1 = pr + 128 (block row
  // space [0,256)); matrix row grow(r) = (r>>6)*256 + jq*64 + (r&63);
  // grow(r+128) = grow(r) + 512.
  const int grow0 = ((pr >> 6) << 8) + jq * 64 + (pr & 63);
  const int grow1 = grow0 + 512;

  // layer0 weights (threads < 512 use these)
  const float4* wl0a = (const float4*)(whh0 + (size_t)grow0 * HID);
  const float4* wl0b = (const float4*)(whh0 + (size_t)grow1 * HID);
  // layer1 weights (threads >= 512 use these)
  const float4* wiA = (const float4*)(wih1 + (size_t)grow0 * HID);
  const float4* wiB = (const float4*)(wih1 + (size_t)grow1 * HID);
  const float4* whA = (const float4*)(whh1 + (size_t)grow0 * HID);
  const float4* whB = (const float4*)(whh1 + (size_t)grow1 * HID);
  const float bsA = bih1[grow0] + bhh1[grow0];
  const float bsB = bih1[grow1] + bhh1[grow1];

  // pointwise role (tid < 256): cell (pb, pj); both layers' c-state here (R9)
  const int pb = tid & 3, pj = (tid >> 2) & 63;
  const int prow = (grp * 4 + pb) * HID + (jq * 64 + pj);
  float c0r = 0.f, c1r = 0.f;

  u32* flags0 = bar;                  // slot bid*16 (64B apart), single-writer
  u32* flags1 = bar + 4096;

  // preload all ids for this group's 4 batches (coalesced, once)
  #pragma unroll
  for (int u = 0; u < 2; ++u) {
    int e = tid + 1024 * u;           // [0, 2048)
    int b = e >> 9, tt = e & 511;
    ids_l[b][tt] = ids[(grp * 4 + b) * TT + tt];
  }

  for (int t = 0; t <= TT + 1; ++t) {
    // ---- wave0: poll 3 peers' flags (single-writer slots, no RMW; R9) ----
    if (wv == 0) {
      const int q = ln & 3;
      const int pbid = ((bid >> 3) << 3) | (q << 1) | (bid & 1);
      u32 need = 0;
      const u32* fp = nullptr;
      if (ln < 4) {
        if (q != jq && t >= 1 && t <= TT) { fp = flags0 + pbid * 16; need = (u32)t; }
      } else if (ln < 8) {
        if (q != jq && t >= 3) { fp = flags1 + pbid * 16; need = (u32)(t - 2); }
      }
      for (;;) {
        bool ok = true;
        if (need) ok = __hip_atomic_load(fp, __ATOMIC_RELAXED, __HIP_MEMORY_SCOPE_AGENT) >= need;
        if (__all(ok)) break;
        __builtin_amdgcn_s_sleep(2);
      }
    }
    __syncthreads();   // A: flags ok + prev-iter gemm done reading hp tiles

    // ---- stage tiles (relaxed agent loads; 4KB each; coalesced; R9) ----
    if (tid < 512) {
      if (t <= TT) {
        const float* h0p = ((t + 1) & 1) ? h0b : h0a;    // h0[t-1]
        const u64* s0 = (const u64*)h0p;
        int e = tid;                                     // [0,512) u64
        u64 v = __hip_atomic_load(s0 + grp * 512 + e, __ATOMIC_RELAXED, __HIP_MEMORY_SCOPE_AGENT);
        *(u64*)&hp0[t & 1][e >> 7][(e & 127) * 2] = v;
      }
    } else {
      if (t >= 2) {
        const float* h1p = ((t + 1) & 1) ? h1b : h1a;    // h1[t-3]
        const u64* s1 = (const u64*)h1p;
        int e = tid - 512;
        u64 v = __hip_atomic_load(s1 + grp * 512 + e, __ATOMIC_RELAXED, __HIP_MEMORY_SCOPE_AGENT);
        *(u64*)&hp1[e >> 7][(e & 127) * 2] = v;
      }
    }
    __syncthreads();   // B: tiles staged

    // ---- CONCURRENT gemms: threads<512 layer0 step t; >=512 layer1 step t-2 ----
    if (tid < 512) {
      if (t < TT) {
        const float* xr = W0 + (size_t)ids_l[tb][t] * GATES;
        float xg0 = xr[grow0], xg1 = xr[grow1];
        const float4* h4 = (const float4*)hp0[t & 1][tb];
        f32x2 aL0={0,0}, aH0={0,0}, aL1={0,0}, aH1={0,0};
        #pragma unroll 8
        for (int k = 0; k < 64; ++k) {
          float4 hv = h4[k];
          float4 q0 = wl0a[k], q1 = wl0b[k];
          aL0 = lo2(q0) * lo2(hv) + aL0; aH0 = hi2(q0) * hi2(hv) + aH0;
          aL1 = lo2(q1) * lo2(hv) + aL1; aH1 = hi2(q1) * hi2(hv) + aH1;
        }
        gs0[pr][tb]       = xg0 + aL0.x + aL0.y + aH0.x + aH0.y;
        gs0[pr + 128][tb] = xg1 + aL1.x + aL1.y + aH1.x + aH1.y;
      }
    } else {
      if (t >= 2) {
        const float4* x4 = (const float4*)hp0[(t - 1) & 1][tb];
        const float4* h4 = (const float4*)hp1[tb];
        f32x2 aL0={0,0}, aH0={0,0}, aL1={0,0}, aH1={0,0};
        #pragma unroll 8
        for (int k = 0; k < 64; ++k) {
          float4 xv = x4[k];
          float4 qi0 = wiA[k], qi1 = wiB[k];
          aL0 = lo2(qi0) * lo2(xv) + aL0; aH0 = hi2(qi0) * hi2(xv) + aH0;
          aL1 = lo2(qi1) * lo2(xv) + aL1; aH1 = hi2(qi1) * hi2(xv) + aH1;
          float4 hv = h4[k];
          float4 qh0 = whA[k], qh1 = whB[k];
          aL0 = lo2(qh0) * lo2(hv) + aL0; aH0 = hi2(qh0) * hi2(hv) + aH0;
          aL1 = lo2(qh1) * lo2(hv) + aL1; aH1 = hi2(qh1) * hi2(hv) + aH1;
        }
        gs1[pr][tb]       = bsA + aL0.x + aL0.y + aH0.x + aH0.y;
        gs1[pr + 128][tb] = bsB + aL1.x + aL1.y + aH1.x + aH1.y;
      }
    }
    __syncthreads();   // C: both gate sets ready

    // ---- layer0 pointwise: store h0[t], then PUBLISH (R9 tail order) ----
    if (t < TT && tid < 256) {
      float gi = sigm(gs0[pj][pb]);
      float gf = sigm(gs0[64 + pj][pb]);
      float gg = tanhf(gs0[128 + pj][pb]);
      float go = sigm(gs0[192 + pj][pb]);
      c0r = fmaf(gf, c0r, gi * gg);
      float* h0n = (t & 1) ? h0b : h0a;
      __hip_atomic_store(&h0n[prow], go * tanhf(c0r),
                         __ATOMIC_RELAXED, __HIP_MEMORY_SCOPE_AGENT);
    }
    __syncthreads();   // D: drains vmcnt(0) -> h0 stores at coherence point
    if (tid == 0 && t < TT)
      __hip_atomic_store(flags0 + bid * 16, (u32)(t + 1),
                         __ATOMIC_RELAXED, __HIP_MEMORY_SCOPE_AGENT);

    // ---- layer1 pointwise: store h1[t-2], publish flags1 (R9) ----
    if (t >= 2 && tid < 256) {
      float gi = sigm(gs1[pj][pb]);
      float gf = sigm(gs1[64 + pj][pb]);
      float gg = tanhf(gs1[128 + pj][pb]);
      float go = sigm(gs1[192 + pj][pb]);
      c1r = fmaf(gf, c1r, gi * gg);
      float* h1n = (t & 1) ? h1b : h1a;   // parity of s = t-2
      __hip_atomic_store(&h1n[prow], go * tanhf(c1r),
                         __ATOMIC_RELAXED, __HIP_MEMORY_SCOPE_AGENT);
    }
    __syncthreads();   // F: drains vmcnt(0) -> h1 stores at coherence point
    if (tid == 0 && t >= 2 && t <= TT)
      __hip_atomic_store(flags1 + bid * 16, (u32)(t - 1),
                         __ATOMIC_RELAXED, __HIP_MEMORY_SCOPE_AGENT);
  }
}

// MLP head: out[b] = fc2_w . relu(fc1_w @ h[b] + fc1_b) + fc2_b
__global__ __launch_bounds__(128) void k_fc(
    const float* __restrict__ hfin,
    const void* __restrict__ fc1w, const void* __restrict__ fc1b,
    const void* __restrict__ fc2w, const void* __restrict__ fc2b,
    const int* __restrict__ flag, void* __restrict__ out) {
  int b = blockIdx.x, j = threadIdx.x;  // 128 threads
  __shared__ float red[128];
  const float* h = hfin + b * HID;
  int isbf = flag[0];
  float acc = isbf ? bf1(((const u16*)fc1b)[j]) : ((const float*)fc1b)[j];
  if (isbf) {
    const u16* w = (const u16*)fc1w + j * HID;
    for (int k = 0; k < HID; k++) acc = fmaf(bf1(w[k]), h[k], acc);
  } else {
    const float* w = (const float*)fc1w + j * HID;
    for (int k = 0; k < HID; k++) acc = fmaf(w[k], h[k], acc);
  }
  acc = fmaxf(acc, 0.f);
  float w2 = isbf ? bf1(((const u16*)fc2w)[j]) : ((const float*)fc2w)[j];
  red[j] = acc * w2;
  __syncthreads();
  for (int s = 64; s > 0; s >>= 1) {
    if (j < s) red[j] += red[j + s];
    __syncthreads();
  }
  if (j == 0) {
    float b2 = isbf ? bf1(((const u16*)fc2b)[0]) : ((const float*)fc2b)[0];
    float r = red[0] + b2;
    if (isbf) ((u16*)out)[b] = f2bf(r);
    else      ((float*)out)[b] = r;
  }
}

extern "C" void kernel_launch(void* const* d_in, const int* in_sizes, int n_in,
                              void* d_out, int out_size, void* d_ws, size_t ws_size,
                              hipStream_t stream) {
  const int* ids   = (const int*)d_in[0];
  const void* emb  = d_in[1];
  const void* wih0 = d_in[2];
  const void* whh0 = d_in[3];
  const void* bih0 = d_in[4];
  const void* bhh0 = d_in[5];
  const void* wih1 = d_in[6];
  const void* whh1 = d_in[7];
  const void* bih1 = d_in[8];
  const void* bhh1 = d_in[9];
  const void* fc1w = d_in[10];
  const void* fc1b = d_in[11];
  const void* fc2w = d_in[12];
  const void* fc2b = d_in[13];

  float* ws = (float*)d_ws;
  int*   flag    = (int*)ws;                  // 16-float pad
  float* W0emb   = ws + 16;                   // 27648
  float* whh0_f  = W0emb  + VOC * GATES;      // 262144
  float* wih1_f  = whh0_f + GATES * HID;      // 262144
  float* whh1_f  = wih1_f + GATES * HID;      // 262144
  float* bih1_f  = whh1_f + GATES * HID;      // 1024
  float* bhh1_f  = bih1_f + GATES;            // 1024
  float* h0A = bhh1_f + GATES;                // 65536 each below
  float* h0B = h0A + BATCH * HID;
  float* c0  = h0B + BATCH * HID;             // reused as flag arrays
  float* h1A = c0  + BATCH * HID;
  float* h1B = h1A + BATCH * HID;
  float* c1  = h1B + BATCH * HID;
  u32*   bar = (u32*)c0;                      // flags0[256*16], flags1[256*16]

  k_detect<<<1, 64, 0, stream>>>((const u16*)bih0, flag);

  k_convert<<<(GATES * HID + 255) / 256, 256, 0, stream>>>(whh0, whh0_f, GATES * HID, flag);
  k_convert<<<(GATES * HID + 255) / 256, 256, 0, stream>>>(wih1, wih1_f, GATES * HID, flag);
  k_convert<<<(GATES * HID + 255) / 256, 256, 0, stream>>>(whh1, whh1_f, GATES * HID, flag);
  k_convert<<<(GATES + 255) / 256, 256, 0, stream>>>(bih1, bih1_f, GATES, flag);
  k_convert<<<(GATES + 255) / 256, 256, 0, stream>>>(bhh1, bhh1_f, GATES, flag);

  // zero h0A,h0B,c0(=flags),h1A,h1B,c1 — also resets flags each replay
  hipMemsetAsync(h0A, 0, (size_t)6 * BATCH * HID * sizeof(float), stream);

  k_prep<<<(VOC * GATES + 255) / 256, 256, 0, stream>>>(emb, wih0, bih0, bhh0, flag, W0emb);

  k_lstm<<<256, 1024, 0, stream>>>(ids, W0emb, whh0_f, wih1_f, whh1_f,
                                   bih1_f, bhh1_f, h0A, h0B, h1A, h1B, bar);

  // L1 step 511 computed at iter t=513 (odd) -> stored into h1B
  k_fc<<<BATCH, 128, 0, stream>>>(h1B, fc1w, fc1b, fc2w, fc2b, flag, d_out);
}